// Round 1
// baseline (615.844 us; speedup 1.0000x reference)
//
#include <hip/hip_runtime.h>
#include <stdint.h>

// ---------- types ----------
typedef __attribute__((ext_vector_type(4))) float f32x4;
typedef __attribute__((ext_vector_type(8))) __bf16 bf8_t;     // MFMA A/B fragment (8 bf16 = 4 VGPR)
typedef __attribute__((ext_vector_type(8))) uint16_t u16x8;   // raw 16B bf16 load/store

typedef __attribute__((address_space(1))) uint8_t as1_u8;
typedef __attribute__((address_space(3))) uint8_t as3_u8;

__device__ inline void async_copy16(const void* g, void* l) {
  __builtin_amdgcn_global_load_lds((const as1_u8*)g, (as3_u8*)l, 16, 0, 0);
}

__device__ inline uint16_t f2bf(float f) {
  uint32_t u = __builtin_bit_cast(uint32_t, f);
  u = (u + 0x7fff + ((u >> 16) & 1)) >> 16;
  return (uint16_t)u;
}
__device__ inline float bf2f(uint16_t h) {
  uint32_t u = ((uint32_t)h) << 16;
  return __builtin_bit_cast(float, u);
}
// XOR swizzle for [R][128B-or-256B-row] bf16 LDS tiles (guide §6 G4)
__device__ inline int swz(int r) { return (((r & 7) ^ ((r >> 3) & 7)) << 4); }

// ---------- rmsnorm: f32 [2048] row -> bf16 ----------
__global__ __launch_bounds__(256) void rmsnorm_kernel(const float* __restrict__ X,
                                                      const float* __restrict__ S,
                                                      uint16_t* __restrict__ O) {
  const int row = blockIdx.x;
  const int tid = threadIdx.x;
  const float* xr = X + (size_t)row * 2048;
  float4 v1 = ((const float4*)xr)[tid * 2];
  float4 v2 = ((const float4*)xr)[tid * 2 + 1];
  float ss = v1.x * v1.x + v1.y * v1.y + v1.z * v1.z + v1.w * v1.w +
             v2.x * v2.x + v2.y * v2.y + v2.z * v2.z + v2.w * v2.w;
  #pragma unroll
  for (int m = 1; m < 64; m <<= 1) ss += __shfl_xor(ss, m);
  __shared__ float wsum[4];
  if ((tid & 63) == 0) wsum[tid >> 6] = ss;
  __syncthreads();
  float tot = wsum[0] + wsum[1] + wsum[2] + wsum[3];
  float inv = rsqrtf(tot * (1.0f / 2048.0f) + 1e-5f);
  const int base = tid * 8;
  const float* sc = S + base;
  float xs[8] = {v1.x, v1.y, v1.z, v1.w, v2.x, v2.y, v2.z, v2.w};
  u16x8 o;
  #pragma unroll
  for (int j = 0; j < 8; j++) o[j] = f2bf(xs[j] * inv * sc[j]);
  *(u16x8*)(O + (size_t)row * 2048 + base) = o;
}

// ---------- transpose+convert: W f32 [K][N] -> WT bf16 [N][K] ----------
__global__ __launch_bounds__(256) void transpose_conv(const float* __restrict__ W,
                                                      uint16_t* __restrict__ WT,
                                                      int K, int N) {
  __shared__ float tile[32][33];
  const int n0 = blockIdx.x * 32, k0 = blockIdx.y * 32;
  const int tx = threadIdx.x, ty = threadIdx.y;  // 32 x 8
  #pragma unroll
  for (int i = 0; i < 4; i++)
    tile[ty + 8 * i][tx] = W[(size_t)(k0 + ty + 8 * i) * N + n0 + tx];
  __syncthreads();
  #pragma unroll
  for (int i = 0; i < 4; i++)
    WT[(size_t)(n0 + ty + 8 * i) * K + k0 + tx] = f2bf(tile[tx][ty + 8 * i]);
}

// ---------- GEMM: C[M,N] = epi(A[M,K]bf16 * BT[N,K]bf16) ----------
enum { EPI_BF16 = 0, EPI_ADDF32 = 1, EPI_SILUMUL = 2 };

template <int EPI>
__global__ __launch_bounds__(256, 2) void gemm_bt(const uint16_t* __restrict__ A,
                                                  const uint16_t* __restrict__ BT,
                                                  void* __restrict__ Cout,
                                                  const void* __restrict__ RES,
                                                  int M, int N, int K) {
  __shared__ uint16_t As[128 * 32];
  __shared__ uint16_t Bs[128 * 32];
  const int tid = threadIdx.x;
  const int lane = tid & 63;
  const int w = tid >> 6;
  const int l15 = lane & 15, l4 = lane >> 4;
  const int m0 = blockIdx.y * 128, n0 = blockIdx.x * 128;
  const int wr = w >> 1, wc = w & 1;

  f32x4 acc[4][4];
  #pragma unroll
  for (int i = 0; i < 4; i++)
    #pragma unroll
    for (int j = 0; j < 4; j++) acc[i][j] = 0.0f;

  for (int kk = 0; kk < K; kk += 32) {
    __syncthreads();
    #pragma unroll
    for (int s = 0; s < 2; s++) {
      const int bu = s * 256 + w * 64;       // wave-uniform 16B-unit base
      const int unit = bu + lane;
      const int row = unit >> 2, ch = unit & 3;
      async_copy16(A + (size_t)(m0 + row) * K + kk + ch * 8, (char*)As + bu * 16);
      async_copy16(BT + (size_t)(n0 + row) * K + kk + ch * 8, (char*)Bs + bu * 16);
    }
    __syncthreads();
    bf8_t a[4], b[4];
    #pragma unroll
    for (int mi = 0; mi < 4; mi++)
      a[mi] = *(const bf8_t*)(As + (wr * 64 + mi * 16 + l15) * 32 + l4 * 8);
    #pragma unroll
    for (int ni = 0; ni < 4; ni++)
      b[ni] = *(const bf8_t*)(Bs + (wc * 64 + ni * 16 + l15) * 32 + l4 * 8);
    #pragma unroll
    for (int mi = 0; mi < 4; mi++)
      #pragma unroll
      for (int ni = 0; ni < 4; ni++)
        acc[mi][ni] = __builtin_amdgcn_mfma_f32_16x16x32_bf16(a[mi], b[ni], acc[mi][ni], 0, 0, 0);
  }

  #pragma unroll
  for (int mi = 0; mi < 4; mi++) {
    #pragma unroll
    for (int ni = 0; ni < 4; ni++) {
      #pragma unroll
      for (int r = 0; r < 4; r++) {
        const int row = m0 + wr * 64 + mi * 16 + l4 * 4 + r;
        const int col = n0 + wc * 64 + ni * 16 + l15;
        const size_t idx = (size_t)row * N + col;
        const float v = acc[mi][ni][r];
        if (EPI == EPI_BF16) {
          ((uint16_t*)Cout)[idx] = f2bf(v);
        } else if (EPI == EPI_ADDF32) {
          ((float*)Cout)[idx] = ((const float*)RES)[idx] + v;
        } else {
          const float g = bf2f(((const uint16_t*)RES)[idx]);
          const float sg = g / (1.0f + __expf(-g));
          ((uint16_t*)Cout)[idx] = f2bf(sg * v);
        }
      }
    }
  }
}

// ---------- flash attention with alibi + causal ----------
// qkv bf16 [2048][6144] (q|k|v each 2048 ch, head h at h*128), alibi f32 [16][2048][2048]
// Y bf16 [2048][2048]. Block: head = blockIdx.y, q-tile(64 rows) = reversed blockIdx.x.
__global__ __launch_bounds__(256, 2) void attn_kernel(const uint16_t* __restrict__ qkv,
                                                      const float* __restrict__ alibi,
                                                      uint16_t* __restrict__ Y) {
  const int h = blockIdx.y;
  const int qt = 31 - blockIdx.x;  // heavy tiles dispatch first
  const int tid = threadIdx.x;
  const int lane = tid & 63;
  const int w = tid >> 6;
  const int l15 = lane & 15, l4 = lane >> 4;

  __shared__ uint16_t Ks[64 * 128];    // [kv][d], swizzled
  __shared__ uint16_t Vs[128 * 64];    // [d][kv] (V^T), swizzled
  __shared__ uint16_t Ps[4][16 * 64];  // per-wave P tile [q][kv], swizzled

  const float scale = 0.08838834764831845f;  // 1/sqrt(128)

  // Q fragments live in registers: wave w owns q rows qt*64 + w*16 + [0,16)
  const int qfr = qt * 64 + w * 16 + l15;
  bf8_t qf[4];
  #pragma unroll
  for (int kc = 0; kc < 4; kc++)
    qf[kc] = *(const bf8_t*)(qkv + (size_t)qfr * 6144 + h * 128 + kc * 32 + l4 * 8);

  f32x4 accy[8];
  #pragma unroll
  for (int i = 0; i < 8; i++) accy[i] = 0.0f;
  float mrun[4], lrun[4];
  #pragma unroll
  for (int r = 0; r < 4; r++) { mrun[r] = -1e30f; lrun[r] = 0.0f; }

  for (int kvt = 0; kvt <= qt; kvt++) {
    const int kv0 = kvt * 64;
    __syncthreads();
    // stage K tile [64][128] (swizzled, b128 writes)
    #pragma unroll
    for (int i = 0; i < 4; i++) {
      const int idx = tid + i * 256;
      const int row = idx >> 4;
      const int cc = (idx & 15) * 8;
      u16x8 k8 = *(const u16x8*)(qkv + (size_t)(kv0 + row) * 6144 + 2048 + h * 128 + cc);
      const int bo = (row * 256 + cc * 2) ^ swz(row);
      *(u16x8*)((char*)Ks + bo) = k8;
    }
    // stage V transposed [128][64] (swizzled, scalar writes)
    #pragma unroll
    for (int i = 0; i < 4; i++) {
      const int idx = tid + i * 256;
      const int kv = idx >> 4;
      const int db = idx & 15;
      u16x8 v8 = *(const u16x8*)(qkv + (size_t)(kv0 + kv) * 6144 + 4096 + h * 128 + db * 8);
      #pragma unroll
      for (int j = 0; j < 8; j++) {
        const int d = db * 8 + j;
        const int bo = (d * 128 + kv * 2) ^ swz(d);
        *(uint16_t*)((char*)Vs + bo) = (uint16_t)v8[j];
      }
    }
    __syncthreads();

    // S = Q K^T * scale + alibi, causal mask
    float s[4][4];  // [nf][r]
    #pragma unroll
    for (int nf = 0; nf < 4; nf++) {
      f32x4 sa = 0.0f;
      const int krow = nf * 16 + l15;
      #pragma unroll
      for (int kc = 0; kc < 4; kc++) {
        bf8_t kb = *(const bf8_t*)((const char*)Ks + ((krow * 256 + kc * 64 + l4 * 16) ^ swz(krow)));
        sa = __builtin_amdgcn_mfma_f32_16x16x32_bf16(qf[kc], kb, sa, 0, 0, 0);
      }
      const int kvcol = kv0 + nf * 16 + l15;
      #pragma unroll
      for (int r = 0; r < 4; r++) {
        const int q = qt * 64 + w * 16 + l4 * 4 + r;
        float sv = sa[r] * scale + alibi[((size_t)h * 2048 + q) * 2048 + kvcol];
        if (kvcol > q) sv = -1e30f;
        s[nf][r] = sv;
      }
    }

    // online softmax (wave-parallel row reduce over the 16 lanes of each row)
    #pragma unroll
    for (int r = 0; r < 4; r++) {
      float rm = fmaxf(fmaxf(s[0][r], s[1][r]), fmaxf(s[2][r], s[3][r]));
      rm = fmaxf(rm, __shfl_xor(rm, 1));
      rm = fmaxf(rm, __shfl_xor(rm, 2));
      rm = fmaxf(rm, __shfl_xor(rm, 4));
      rm = fmaxf(rm, __shfl_xor(rm, 8));
      const float mnew = fmaxf(mrun[r], rm);
      const float alpha = __expf(mrun[r] - mnew);
      mrun[r] = mnew;
      float rs = 0.0f;
      #pragma unroll
      for (int nf = 0; nf < 4; nf++) {
        const float p = __expf(s[nf][r] - mnew);
        s[nf][r] = p;
        rs += p;
      }
      rs += __shfl_xor(rs, 1);
      rs += __shfl_xor(rs, 2);
      rs += __shfl_xor(rs, 4);
      rs += __shfl_xor(rs, 8);
      lrun[r] = lrun[r] * alpha + rs;
      #pragma unroll
      for (int df = 0; df < 8; df++) accy[df][r] *= alpha;
    }

    // P -> LDS (bf16, swizzled), wave-private region
    #pragma unroll
    for (int nf = 0; nf < 4; nf++) {
      #pragma unroll
      for (int r = 0; r < 4; r++) {
        const int rq = l4 * 4 + r;
        const int bo = (rq * 128 + (nf * 16 + l15) * 2) ^ swz(rq);
        *(uint16_t*)((char*)Ps[w] + bo) = f2bf(s[nf][r]);
      }
    }

    // PV: accy += P * V
    #pragma unroll
    for (int kk = 0; kk < 2; kk++) {
      bf8_t pa = *(const bf8_t*)((const char*)Ps[w] + ((l15 * 128 + kk * 64 + l4 * 16) ^ swz(l15)));
      #pragma unroll
      for (int df = 0; df < 8; df++) {
        const int vr = df * 16 + l15;
        bf8_t vb = *(const bf8_t*)((const char*)Vs + ((vr * 128 + kk * 64 + l4 * 16) ^ swz(vr)));
        accy[df] = __builtin_amdgcn_mfma_f32_16x16x32_bf16(pa, vb, accy[df], 0, 0, 0);
      }
    }
  }

  // epilogue: Y[q][h*128+d] = accy / lsum
  #pragma unroll
  for (int df = 0; df < 8; df++) {
    #pragma unroll
    for (int r = 0; r < 4; r++) {
      const int row = qt * 64 + w * 16 + l4 * 4 + r;
      const int col = h * 128 + df * 16 + l15;
      Y[(size_t)row * 2048 + col] = f2bf(accy[df][r] / lrun[r]);
    }
  }
}

// ---------- launch ----------
extern "C" void kernel_launch(void* const* d_in, const int* in_sizes, int n_in,
                              void* d_out, int out_size, void* d_ws, size_t ws_size,
                              hipStream_t stream) {
  const float* x      = (const float*)d_in[0];
  const float* alibi  = (const float*)d_in[1];
  const float* w_attn = (const float*)d_in[2];
  const float* w_proj = (const float*)d_in[3];
  const float* w_fc1  = (const float*)d_in[4];
  const float* w_fc2  = (const float*)d_in[5];
  const float* w_mp   = (const float*)d_in[6];
  const float* rms1   = (const float*)d_in[7];
  const float* rms2   = (const float*)d_in[8];
  float* out = (float*)d_out;

  char* ws = (char*)d_ws;
  uint16_t* xn      = (uint16_t*)(ws + 0);          //  8.39 MB [2048][2048]
  uint16_t* qkv     = (uint16_t*)(ws + 8388608);    // 25.17 MB [2048][6144]
  uint16_t* y       = (uint16_t*)(ws + 33554432);   //  8.39 MB [2048][2048]
  uint16_t* g1      = (uint16_t*)(ws + 41943040);   // 23.07 MB [2048][5632]
  uint16_t* hbuf    = (uint16_t*)(ws + 65011712);   // 23.07 MB [2048][5632]
  uint16_t* wt_attn = (uint16_t*)(ws + 88080384);   // 25.17 MB [6144][2048]
  uint16_t* wt_proj = (uint16_t*)(ws + 113246208);  //  8.39 MB [2048][2048]
  uint16_t* wt_fc1  = (uint16_t*)(ws + 121634816);  // 23.07 MB [5632][2048]
  uint16_t* wt_fc2  = (uint16_t*)(ws + 144703488);  // 23.07 MB [5632][2048]
  uint16_t* wt_mp   = (uint16_t*)(ws + 167772160);  // 23.07 MB [2048][5632]

  const dim3 tb(32, 8);
  transpose_conv<<<dim3(6144 / 32, 2048 / 32), tb, 0, stream>>>(w_attn, wt_attn, 2048, 6144);
  transpose_conv<<<dim3(2048 / 32, 2048 / 32), tb, 0, stream>>>(w_proj, wt_proj, 2048, 2048);
  transpose_conv<<<dim3(5632 / 32, 2048 / 32), tb, 0, stream>>>(w_fc1, wt_fc1, 2048, 5632);
  transpose_conv<<<dim3(5632 / 32, 2048 / 32), tb, 0, stream>>>(w_fc2, wt_fc2, 2048, 5632);
  transpose_conv<<<dim3(2048 / 32, 5632 / 32), tb, 0, stream>>>(w_mp, wt_mp, 5632, 2048);

  rmsnorm_kernel<<<2048, 256, 0, stream>>>(x, rms1, xn);

  gemm_bt<EPI_BF16><<<dim3(6144 / 128, 2048 / 128), 256, 0, stream>>>(
      xn, wt_attn, qkv, nullptr, 2048, 6144, 2048);

  attn_kernel<<<dim3(32, 16), 256, 0, stream>>>(qkv, alibi, y);

  gemm_bt<EPI_ADDF32><<<dim3(2048 / 128, 2048 / 128), 256, 0, stream>>>(
      y, wt_proj, out, x, 2048, 2048, 2048);

  rmsnorm_kernel<<<2048, 256, 0, stream>>>(out, rms2, xn);

  gemm_bt<EPI_BF16><<<dim3(5632 / 128, 2048 / 128), 256, 0, stream>>>(
      xn, wt_fc1, g1, nullptr, 2048, 5632, 2048);

  gemm_bt<EPI_SILUMUL><<<dim3(5632 / 128, 2048 / 128), 256, 0, stream>>>(
      xn, wt_fc2, hbuf, g1, 2048, 5632, 2048);

  gemm_bt<EPI_ADDF32><<<dim3(2048 / 128, 2048 / 128), 256, 0, stream>>>(
      hbuf, wt_mp, out, out, 2048, 2048, 5632);
}

// Round 2
// 589.592 us; speedup vs baseline: 1.0445x; 1.0445x over previous
//
#include <hip/hip_runtime.h>
#include <stdint.h>

// ---------- types ----------
typedef __attribute__((ext_vector_type(4))) float f32x4;
typedef __attribute__((ext_vector_type(8))) __bf16 bf8_t;     // MFMA A/B fragment (8 bf16 = 4 VGPR)
typedef __attribute__((ext_vector_type(8))) uint16_t u16x8;   // raw 16B bf16 load/store
typedef __attribute__((ext_vector_type(4))) uint16_t u16x4;   // raw 8B bf16 store

typedef __attribute__((address_space(1))) uint8_t as1_u8;
typedef __attribute__((address_space(3))) uint8_t as3_u8;

__device__ inline void async_copy16(const void* g, void* l) {
  __builtin_amdgcn_global_load_lds((const as1_u8*)g, (as3_u8*)l, 16, 0, 0);
}

__device__ inline uint16_t f2bf(float f) {
  uint32_t u = __builtin_bit_cast(uint32_t, f);
  u = (u + 0x7fff + ((u >> 16) & 1)) >> 16;
  return (uint16_t)u;
}
__device__ inline float bf2f(uint16_t h) {
  uint32_t u = ((uint32_t)h) << 16;
  return __builtin_bit_cast(float, u);
}
// XOR swizzle for 256B-row bf16 LDS tiles (16 chunks of 16B per row)
__device__ inline int swz(int r) { return (((r & 7) ^ ((r >> 3) & 7)) << 4); }
// XOR swizzle for 128B-row bf16 LDS tiles (8 chunks of 16B per row)
__device__ inline int vswz(int r) { return ((r & 7) << 4); }

// ---------- rmsnorm: f32 [2048] row -> bf16 ----------
__global__ __launch_bounds__(256) void rmsnorm_kernel(const float* __restrict__ X,
                                                      const float* __restrict__ S,
                                                      uint16_t* __restrict__ O) {
  const int row = blockIdx.x;
  const int tid = threadIdx.x;
  const float* xr = X + (size_t)row * 2048;
  float4 v1 = ((const float4*)xr)[tid * 2];
  float4 v2 = ((const float4*)xr)[tid * 2 + 1];
  float ss = v1.x * v1.x + v1.y * v1.y + v1.z * v1.z + v1.w * v1.w +
             v2.x * v2.x + v2.y * v2.y + v2.z * v2.z + v2.w * v2.w;
  #pragma unroll
  for (int m = 1; m < 64; m <<= 1) ss += __shfl_xor(ss, m);
  __shared__ float wsum[4];
  if ((tid & 63) == 0) wsum[tid >> 6] = ss;
  __syncthreads();
  float tot = wsum[0] + wsum[1] + wsum[2] + wsum[3];
  float inv = rsqrtf(tot * (1.0f / 2048.0f) + 1e-5f);
  const int base = tid * 8;
  const float* sc = S + base;
  float xs[8] = {v1.x, v1.y, v1.z, v1.w, v2.x, v2.y, v2.z, v2.w};
  u16x8 o;
  #pragma unroll
  for (int j = 0; j < 8; j++) o[j] = f2bf(xs[j] * inv * sc[j]);
  *(u16x8*)(O + (size_t)row * 2048 + base) = o;
}

// ---------- transpose+convert: W f32 [K][N] -> WT bf16 [N][K] ----------
__global__ __launch_bounds__(256) void transpose_conv(const float* __restrict__ W,
                                                      uint16_t* __restrict__ WT,
                                                      int K, int N) {
  __shared__ float tile[32][33];
  const int n0 = blockIdx.x * 32, k0 = blockIdx.y * 32;
  const int tx = threadIdx.x, ty = threadIdx.y;  // 32 x 8
  #pragma unroll
  for (int i = 0; i < 4; i++)
    tile[ty + 8 * i][tx] = W[(size_t)(k0 + ty + 8 * i) * N + n0 + tx];
  __syncthreads();
  #pragma unroll
  for (int i = 0; i < 4; i++)
    WT[(size_t)(n0 + ty + 8 * i) * K + k0 + tx] = f2bf(tile[tx][ty + 8 * i]);
}

// ---------- GEMM: C[M,N] = epi(A[M,K]bf16 * BT[N,K]bf16) ----------
enum { EPI_BF16 = 0, EPI_ADDF32 = 1, EPI_SILUMUL = 2, EPI_QKV = 3 };

template <int EPI>
__global__ __launch_bounds__(256, 2) void gemm_bt(const uint16_t* __restrict__ A,
                                                  const uint16_t* __restrict__ BT,
                                                  void* __restrict__ Cout,
                                                  const void* __restrict__ RES,
                                                  void* __restrict__ Cout2,
                                                  int M, int N, int K) {
  __shared__ uint16_t As[128 * 32];
  __shared__ uint16_t Bs[128 * 32];
  const int tid = threadIdx.x;
  const int lane = tid & 63;
  const int w = tid >> 6;
  const int l15 = lane & 15, l4 = lane >> 4;
  const int m0 = blockIdx.y * 128, n0 = blockIdx.x * 128;
  const int wr = w >> 1, wc = w & 1;

  f32x4 acc[4][4];
  #pragma unroll
  for (int i = 0; i < 4; i++)
    #pragma unroll
    for (int j = 0; j < 4; j++) acc[i][j] = 0.0f;

  for (int kk = 0; kk < K; kk += 32) {
    __syncthreads();
    #pragma unroll
    for (int s = 0; s < 2; s++) {
      const int bu = s * 256 + w * 64;       // wave-uniform 16B-unit base
      const int unit = bu + lane;
      const int row = unit >> 2, ch = unit & 3;
      async_copy16(A + (size_t)(m0 + row) * K + kk + ch * 8, (char*)As + bu * 16);
      async_copy16(BT + (size_t)(n0 + row) * K + kk + ch * 8, (char*)Bs + bu * 16);
    }
    __syncthreads();
    bf8_t a[4], b[4];
    #pragma unroll
    for (int mi = 0; mi < 4; mi++)
      a[mi] = *(const bf8_t*)(As + (wr * 64 + mi * 16 + l15) * 32 + l4 * 8);
    #pragma unroll
    for (int ni = 0; ni < 4; ni++)
      b[ni] = *(const bf8_t*)(Bs + (wc * 64 + ni * 16 + l15) * 32 + l4 * 8);
    #pragma unroll
    for (int mi = 0; mi < 4; mi++)
      #pragma unroll
      for (int ni = 0; ni < 4; ni++)
        acc[mi][ni] = __builtin_amdgcn_mfma_f32_16x16x32_bf16(a[mi], b[ni], acc[mi][ni], 0, 0, 0);
  }

  #pragma unroll
  for (int mi = 0; mi < 4; mi++) {
    #pragma unroll
    for (int ni = 0; ni < 4; ni++) {
      const int row0 = m0 + wr * 64 + mi * 16 + l4 * 4;
      const int col = n0 + wc * 64 + ni * 16 + l15;
      if (EPI == EPI_QKV && col >= 4096) {
        // V third: write transposed vT[d][t], 4 consecutive t = 8B store
        u16x4 pk;
        #pragma unroll
        for (int r = 0; r < 4; r++) pk[r] = f2bf(acc[mi][ni][r]);
        *(u16x4*)((uint16_t*)Cout2 + (size_t)(col - 4096) * 2048 + row0) = pk;
      } else {
        #pragma unroll
        for (int r = 0; r < 4; r++) {
          const size_t idx = (size_t)(row0 + r) * N + col;
          const float v = acc[mi][ni][r];
          if (EPI == EPI_BF16 || EPI == EPI_QKV) {
            ((uint16_t*)Cout)[idx] = f2bf(v);
          } else if (EPI == EPI_ADDF32) {
            ((float*)Cout)[idx] = ((const float*)RES)[idx] + v;
          } else {
            const float g = bf2f(((const uint16_t*)RES)[idx]);
            const float sg = g / (1.0f + __expf(-g));
            ((uint16_t*)Cout)[idx] = f2bf(sg * v);
          }
        }
      }
    }
  }
}

// ---------- flash attention with alibi + causal ----------
// qkv bf16 [2048][6144] (q|k thirds used), vT bf16 [2048 d][2048 t],
// alibi f32 [16][2048][2048], Y bf16 [2048][2048].
// 2-deep pipeline: one barrier/iter; K/V double-buffered via global_load_lds
// (pre-swizzled source); alibi prefetched one tile ahead into registers.
__global__ __launch_bounds__(256, 2) void attn_kernel(const uint16_t* __restrict__ qkv,
                                                      const uint16_t* __restrict__ vT,
                                                      const float* __restrict__ alibi,
                                                      uint16_t* __restrict__ Y) {
  const int h = blockIdx.y;
  const int qt = 31 - blockIdx.x;  // heavy tiles dispatch first
  const int tid = threadIdx.x;
  const int lane = tid & 63;
  const int w = tid >> 6;
  const int l15 = lane & 15, l4 = lane >> 4;

  __shared__ uint16_t Ks[2][64 * 128];  // [kv][d], swizzled (swz)
  __shared__ uint16_t Vs[2][128 * 64];  // [d][kv] (V^T), swizzled (vswz)
  __shared__ uint16_t Ps[4][16 * 64];   // per-wave P tile [q][kv], swizzled

  const float scale = 0.08838834764831845f;  // 1/sqrt(128)

  // stage K tile [64][128] + V^T tile [128][64] into buffer b, tile base kv0.
  // LDS dest is linear (wave-uniform base + lane*16); source chunk index is
  // inverse-swizzled so that reads with swz()/vswz() see the right data.
  auto stage = [&](int kv0, int b) {
    #pragma unroll
    for (int i = 0; i < 4; i++) {
      const int u = tid + i * 256;          // 16B unit 0..1023
      const int r = u >> 4;                 // K row
      const int c = (u & 15) ^ ((r & 7) ^ ((r >> 3) & 7));
      async_copy16(qkv + (size_t)(kv0 + r) * 6144 + 2048 + h * 128 + c * 8,
                   (char*)Ks[b] + u * 16);
    }
    #pragma unroll
    for (int i = 0; i < 4; i++) {
      const int u = tid + i * 256;
      const int r = u >> 3;                 // V^T row (d)
      const int c = (u & 7) ^ (r & 7);
      async_copy16(vT + (size_t)(h * 128 + r) * 2048 + kv0 + c * 8,
                   (char*)Vs[b] + u * 16);
    }
  };
  auto load_al = [&](int kv0, float (&al)[4][4]) {
    #pragma unroll
    for (int r = 0; r < 4; r++) {
      const size_t rowb = ((size_t)h * 2048 + (qt * 64 + w * 16 + l4 * 4 + r)) * 2048;
      #pragma unroll
      for (int nf = 0; nf < 4; nf++)
        al[nf][r] = alibi[rowb + kv0 + nf * 16 + l15];
    }
  };

  // Q fragments in registers: wave w owns q rows qt*64 + w*16 + [0,16)
  const int qrow = qt * 64 + w * 16 + l15;
  bf8_t qf[4];
  #pragma unroll
  for (int kc = 0; kc < 4; kc++)
    qf[kc] = *(const bf8_t*)(qkv + (size_t)qrow * 6144 + h * 128 + kc * 32 + l4 * 8);

  f32x4 accy[8];
  #pragma unroll
  for (int i = 0; i < 8; i++) accy[i] = 0.0f;
  float mrun[4], lrun[4];
  #pragma unroll
  for (int r = 0; r < 4; r++) { mrun[r] = -1e30f; lrun[r] = 0.0f; }

  // prologue: stage tile 0, load alibi tile 0
  stage(0, 0);
  float al[4][4];
  load_al(0, al);

  for (int kvt = 0; kvt <= qt; kvt++) {
    const int b = kvt & 1;
    const int kv0 = kvt * 64;
    __syncthreads();  // staging for tile kvt (and its alibi) drained here

    // prefetch next tile: alibi regs first (so their vmcnt wait doesn't
    // cover the staging loads), then K/V global_load_lds into buf b^1
    const int kvn = (kvt < qt) ? (kvt + 1) : qt;
    float aln[4][4];
    load_al(kvn * 64, aln);
    stage(kvn * 64, b ^ 1);

    // S = Q K^T * scale + alibi, causal mask
    float s[4][4];  // [nf][r]
    #pragma unroll
    for (int nf = 0; nf < 4; nf++) {
      f32x4 sa = 0.0f;
      const int krow = nf * 16 + l15;
      #pragma unroll
      for (int kc = 0; kc < 4; kc++) {
        bf8_t kb = *(const bf8_t*)((const char*)Ks[b] +
                                   ((krow * 256 + kc * 64 + l4 * 16) ^ swz(krow)));
        sa = __builtin_amdgcn_mfma_f32_16x16x32_bf16(qf[kc], kb, sa, 0, 0, 0);
      }
      const int kvcol = kv0 + nf * 16 + l15;
      #pragma unroll
      for (int r = 0; r < 4; r++) {
        const int q = qt * 64 + w * 16 + l4 * 4 + r;
        float sv = sa[r] * scale + al[nf][r];
        if (kvcol > q) sv = -1e30f;
        s[nf][r] = sv;
      }
    }

    // online softmax (wave-parallel row reduce over the 16 lanes of each row)
    #pragma unroll
    for (int r = 0; r < 4; r++) {
      float rm = fmaxf(fmaxf(s[0][r], s[1][r]), fmaxf(s[2][r], s[3][r]));
      rm = fmaxf(rm, __shfl_xor(rm, 1));
      rm = fmaxf(rm, __shfl_xor(rm, 2));
      rm = fmaxf(rm, __shfl_xor(rm, 4));
      rm = fmaxf(rm, __shfl_xor(rm, 8));
      const float mnew = fmaxf(mrun[r], rm);
      const float alpha = __expf(mrun[r] - mnew);
      mrun[r] = mnew;
      float rs = 0.0f;
      #pragma unroll
      for (int nf = 0; nf < 4; nf++) {
        const float p = __expf(s[nf][r] - mnew);
        s[nf][r] = p;
        rs += p;
      }
      rs += __shfl_xor(rs, 1);
      rs += __shfl_xor(rs, 2);
      rs += __shfl_xor(rs, 4);
      rs += __shfl_xor(rs, 8);
      lrun[r] = lrun[r] * alpha + rs;
      #pragma unroll
      for (int df = 0; df < 8; df++) accy[df][r] *= alpha;
    }

    // P -> LDS (bf16, swizzled), wave-private region (lgkm dependency only —
    // no barrier needed between write and read within the same wave)
    #pragma unroll
    for (int nf = 0; nf < 4; nf++) {
      #pragma unroll
      for (int r = 0; r < 4; r++) {
        const int rq = l4 * 4 + r;
        const int bo = (rq * 128 + (nf * 16 + l15) * 2) ^ vswz(rq);
        *(uint16_t*)((char*)Ps[w] + bo) = f2bf(s[nf][r]);
      }
    }

    // PV: accy += P * V
    #pragma unroll
    for (int kk = 0; kk < 2; kk++) {
      bf8_t pa = *(const bf8_t*)((const char*)Ps[w] +
                                 ((l15 * 128 + kk * 64 + l4 * 16) ^ vswz(l15)));
      #pragma unroll
      for (int df = 0; df < 8; df++) {
        const int vr = df * 16 + l15;
        bf8_t vb = *(const bf8_t*)((const char*)Vs[b] +
                                   ((vr * 128 + kk * 64 + l4 * 16) ^ vswz(vr)));
        accy[df] = __builtin_amdgcn_mfma_f32_16x16x32_bf16(pa, vb, accy[df], 0, 0, 0);
      }
    }

    // rotate alibi prefetch
    #pragma unroll
    for (int nf = 0; nf < 4; nf++)
      #pragma unroll
      for (int r = 0; r < 4; r++) al[nf][r] = aln[nf][r];
  }

  // epilogue: Y[q][h*128+d] = accy / lsum
  #pragma unroll
  for (int df = 0; df < 8; df++) {
    #pragma unroll
    for (int r = 0; r < 4; r++) {
      const int row = qt * 64 + w * 16 + l4 * 4 + r;
      const int col = h * 128 + df * 16 + l15;
      Y[(size_t)row * 2048 + col] = f2bf(accy[df][r] / lrun[r]);
    }
  }
}

// ---------- launch ----------
extern "C" void kernel_launch(void* const* d_in, const int* in_sizes, int n_in,
                              void* d_out, int out_size, void* d_ws, size_t ws_size,
                              hipStream_t stream) {
  const float* x      = (const float*)d_in[0];
  const float* alibi  = (const float*)d_in[1];
  const float* w_attn = (const float*)d_in[2];
  const float* w_proj = (const float*)d_in[3];
  const float* w_fc1  = (const float*)d_in[4];
  const float* w_fc2  = (const float*)d_in[5];
  const float* w_mp   = (const float*)d_in[6];
  const float* rms1   = (const float*)d_in[7];
  const float* rms2   = (const float*)d_in[8];
  float* out = (float*)d_out;

  char* ws = (char*)d_ws;
  uint16_t* xn      = (uint16_t*)(ws + 0);          //  8.39 MB [2048][2048]
  uint16_t* qkv     = (uint16_t*)(ws + 8388608);    // 25.17 MB [2048][6144] (q|k used)
  uint16_t* y       = (uint16_t*)(ws + 33554432);   //  8.39 MB [2048][2048]
  uint16_t* g1      = (uint16_t*)(ws + 41943040);   // 23.07 MB [2048][5632]
  uint16_t* hbuf    = (uint16_t*)(ws + 65011712);   // 23.07 MB [2048][5632]
  uint16_t* wt_attn = (uint16_t*)(ws + 88080384);   // 25.17 MB [6144][2048]
  uint16_t* wt_proj = (uint16_t*)(ws + 113246208);  //  8.39 MB [2048][2048]
  uint16_t* wt_fc1  = (uint16_t*)(ws + 121634816);  // 23.07 MB [5632][2048]
  uint16_t* wt_fc2  = (uint16_t*)(ws + 144703488);  // 23.07 MB [5632][2048]
  uint16_t* wt_mp   = (uint16_t*)(ws + 167772160);  // 23.07 MB [2048][5632]
  uint16_t* vT      = (uint16_t*)(ws + 190840832);  //  8.39 MB [2048 d][2048 t]

  const dim3 tb(32, 8);
  transpose_conv<<<dim3(6144 / 32, 2048 / 32), tb, 0, stream>>>(w_attn, wt_attn, 2048, 6144);
  transpose_conv<<<dim3(2048 / 32, 2048 / 32), tb, 0, stream>>>(w_proj, wt_proj, 2048, 2048);
  transpose_conv<<<dim3(5632 / 32, 2048 / 32), tb, 0, stream>>>(w_fc1, wt_fc1, 2048, 5632);
  transpose_conv<<<dim3(5632 / 32, 2048 / 32), tb, 0, stream>>>(w_fc2, wt_fc2, 2048, 5632);
  transpose_conv<<<dim3(2048 / 32, 5632 / 32), tb, 0, stream>>>(w_mp, wt_mp, 5632, 2048);

  rmsnorm_kernel<<<2048, 256, 0, stream>>>(x, rms1, xn);

  gemm_bt<EPI_QKV><<<dim3(6144 / 128, 2048 / 128), 256, 0, stream>>>(
      xn, wt_attn, qkv, nullptr, vT, 2048, 6144, 2048);

  attn_kernel<<<dim3(32, 16), 256, 0, stream>>>(qkv, vT, alibi, y);

  gemm_bt<EPI_ADDF32><<<dim3(2048 / 128, 2048 / 128), 256, 0, stream>>>(
      y, wt_proj, out, x, nullptr, 2048, 2048, 2048);

  rmsnorm_kernel<<<2048, 256, 0, stream>>>(out, rms2, xn);

  gemm_bt<EPI_BF16><<<dim3(5632 / 128, 2048 / 128), 256, 0, stream>>>(
      xn, wt_fc1, g1, nullptr, nullptr, 2048, 5632, 2048);

  gemm_bt<EPI_SILUMUL><<<dim3(5632 / 128, 2048 / 128), 256, 0, stream>>>(
      xn, wt_fc2, hbuf, g1, nullptr, 2048, 5632, 2048);

  gemm_bt<EPI_ADDF32><<<dim3(2048 / 128, 2048 / 128), 256, 0, stream>>>(
      hbuf, wt_mp, out, out, nullptr, 2048, 2048, 5632);
}

// Round 3
// 589.510 us; speedup vs baseline: 1.0447x; 1.0001x over previous
//
#include <hip/hip_runtime.h>
#include <stdint.h>

// ---------- types ----------
typedef __attribute__((ext_vector_type(4))) float f32x4;
typedef __attribute__((ext_vector_type(8))) __bf16 bf8_t;     // MFMA A/B fragment (8 bf16 = 4 VGPR)
typedef __attribute__((ext_vector_type(8))) uint16_t u16x8;   // raw 16B bf16 load/store

typedef __attribute__((address_space(1))) uint8_t as1_u8;
typedef __attribute__((address_space(3))) uint8_t as3_u8;

__device__ inline void async_copy16(const void* g, void* l) {
  __builtin_amdgcn_global_load_lds((const as1_u8*)g, (as3_u8*)l, 16, 0, 0);
}

__device__ inline uint16_t f2bf(float f) {
  uint32_t u = __builtin_bit_cast(uint32_t, f);
  u = (u + 0x7fff + ((u >> 16) & 1)) >> 16;
  return (uint16_t)u;
}
__device__ inline float bf2f(uint16_t h) {
  uint32_t u = ((uint32_t)h) << 16;
  return __builtin_bit_cast(float, u);
}
// XOR swizzle for 256B-row bf16 LDS tiles (16 chunks of 16B per row)
__device__ inline int swz(int r) { return (((r & 7) ^ ((r >> 3) & 7)) << 4); }
// XOR swizzle for 128B-row bf16 LDS tiles (8 chunks of 16B per row)
__device__ inline int vswz(int r) { return ((r & 7) << 4); }

// ---------- rmsnorm: f32 [2048] row -> bf16 ----------
__global__ __launch_bounds__(256) void rmsnorm_kernel(const float* __restrict__ X,
                                                      const float* __restrict__ S,
                                                      uint16_t* __restrict__ O) {
  const int row = blockIdx.x;
  const int tid = threadIdx.x;
  const float* xr = X + (size_t)row * 2048;
  float4 v1 = ((const float4*)xr)[tid * 2];
  float4 v2 = ((const float4*)xr)[tid * 2 + 1];
  float ss = v1.x * v1.x + v1.y * v1.y + v1.z * v1.z + v1.w * v1.w +
             v2.x * v2.x + v2.y * v2.y + v2.z * v2.z + v2.w * v2.w;
  #pragma unroll
  for (int m = 1; m < 64; m <<= 1) ss += __shfl_xor(ss, m);
  __shared__ float wsum[4];
  if ((tid & 63) == 0) wsum[tid >> 6] = ss;
  __syncthreads();
  float tot = wsum[0] + wsum[1] + wsum[2] + wsum[3];
  float inv = rsqrtf(tot * (1.0f / 2048.0f) + 1e-5f);
  const int base = tid * 8;
  const float* sc = S + base;
  float xs[8] = {v1.x, v1.y, v1.z, v1.w, v2.x, v2.y, v2.z, v2.w};
  u16x8 o;
  #pragma unroll
  for (int j = 0; j < 8; j++) o[j] = f2bf(xs[j] * inv * sc[j]);
  *(u16x8*)(O + (size_t)row * 2048 + base) = o;
}

// ---------- transpose+convert: W f32 [K][N] -> WT bf16 [N][K], 64x64 tiles ----------
__global__ __launch_bounds__(256) void transpose_conv(const float* __restrict__ W,
                                                      uint16_t* __restrict__ WT,
                                                      int K, int N) {
  __shared__ float tile[64][65];  // pad 65: <=2-way banks in both phases
  const int n0 = blockIdx.x * 64, k0 = blockIdx.y * 64;
  const int tid = threadIdx.x;
  const int lr = tid >> 4;        // 0..15
  const int lc = (tid & 15) * 4;  // 0..60
  #pragma unroll
  for (int i = 0; i < 4; i++) {
    const float4 v = *(const float4*)&W[(size_t)(k0 + lr + i * 16) * N + n0 + lc];
    tile[lr + i * 16][lc] = v.x;
    tile[lr + i * 16][lc + 1] = v.y;
    tile[lr + i * 16][lc + 2] = v.z;
    tile[lr + i * 16][lc + 3] = v.w;
  }
  __syncthreads();
  const int tn = tid >> 3;        // 0..31
  const int tk = (tid & 7) * 8;   // 0..56
  #pragma unroll
  for (int i = 0; i < 2; i++) {
    u16x8 o;
    #pragma unroll
    for (int j = 0; j < 8; j++) o[j] = f2bf(tile[tk + j][tn + i * 32]);
    *(u16x8*)&WT[(size_t)(n0 + tn + i * 32) * K + k0 + tk] = o;
  }
}

// ---------- transpose V third of qkv: bf16 [2048 t][ch 4096+c] -> vT [2048 c][2048 t] ----------
__global__ __launch_bounds__(256) void transpose_v(const uint16_t* __restrict__ qkv,
                                                   uint16_t* __restrict__ vT) {
  __shared__ uint16_t tile[64][68];  // [c][t], pad 68 -> ~2-way banks
  const int t0 = blockIdx.x * 64;
  const int c0 = blockIdx.y * 64;
  const int tid = threadIdx.x;
  const int lr = tid >> 3;        // 0..31
  const int lc = (tid & 7) * 8;   // 0..56
  #pragma unroll
  for (int i = 0; i < 2; i++) {
    const int r = lr + i * 32;
    u16x8 v = *(const u16x8*)&qkv[(size_t)(t0 + r) * 6144 + 4096 + c0 + lc];
    #pragma unroll
    for (int j = 0; j < 8; j++) tile[lc + j][r] = v[j];
  }
  __syncthreads();
  #pragma unroll
  for (int i = 0; i < 2; i++) {
    const int c = lr + i * 32;
    u16x8 o = *(const u16x8*)&tile[c][lc];
    *(u16x8*)&vT[(size_t)(c0 + c) * 2048 + t0 + lc] = o;
  }
}

// ---------- GEMM: C[M,N] = epi(A[M,K]bf16 * BT[N,K]bf16) ----------
enum { EPI_BF16 = 0, EPI_ADDF32 = 1, EPI_SILUMUL = 2 };

template <int EPI>
__global__ __launch_bounds__(256, 2) void gemm_bt(const uint16_t* __restrict__ A,
                                                  const uint16_t* __restrict__ BT,
                                                  void* __restrict__ Cout,
                                                  const void* __restrict__ RES,
                                                  int M, int N, int K) {
  __shared__ uint16_t As[128 * 32];
  __shared__ uint16_t Bs[128 * 32];
  const int tid = threadIdx.x;
  const int lane = tid & 63;
  const int w = tid >> 6;
  const int l15 = lane & 15, l4 = lane >> 4;
  const int m0 = blockIdx.y * 128, n0 = blockIdx.x * 128;
  const int wr = w >> 1, wc = w & 1;

  f32x4 acc[4][4];
  #pragma unroll
  for (int i = 0; i < 4; i++)
    #pragma unroll
    for (int j = 0; j < 4; j++) acc[i][j] = 0.0f;

  for (int kk = 0; kk < K; kk += 32) {
    __syncthreads();
    #pragma unroll
    for (int s = 0; s < 2; s++) {
      const int bu = s * 256 + w * 64;       // wave-uniform 16B-unit base
      const int unit = bu + lane;
      const int row = unit >> 2, ch = unit & 3;
      async_copy16(A + (size_t)(m0 + row) * K + kk + ch * 8, (char*)As + bu * 16);
      async_copy16(BT + (size_t)(n0 + row) * K + kk + ch * 8, (char*)Bs + bu * 16);
    }
    __syncthreads();
    bf8_t a[4], b[4];
    #pragma unroll
    for (int mi = 0; mi < 4; mi++)
      a[mi] = *(const bf8_t*)(As + (wr * 64 + mi * 16 + l15) * 32 + l4 * 8);
    #pragma unroll
    for (int ni = 0; ni < 4; ni++)
      b[ni] = *(const bf8_t*)(Bs + (wc * 64 + ni * 16 + l15) * 32 + l4 * 8);
    #pragma unroll
    for (int mi = 0; mi < 4; mi++)
      #pragma unroll
      for (int ni = 0; ni < 4; ni++)
        acc[mi][ni] = __builtin_amdgcn_mfma_f32_16x16x32_bf16(a[mi], b[ni], acc[mi][ni], 0, 0, 0);
  }

  #pragma unroll
  for (int mi = 0; mi < 4; mi++) {
    #pragma unroll
    for (int ni = 0; ni < 4; ni++) {
      #pragma unroll
      for (int r = 0; r < 4; r++) {
        const int row = m0 + wr * 64 + mi * 16 + l4 * 4 + r;
        const int col = n0 + wc * 64 + ni * 16 + l15;
        const size_t idx = (size_t)row * N + col;
        const float v = acc[mi][ni][r];
        if (EPI == EPI_BF16) {
          ((uint16_t*)Cout)[idx] = f2bf(v);
        } else if (EPI == EPI_ADDF32) {
          ((float*)Cout)[idx] = ((const float*)RES)[idx] + v;
        } else {
          const float g = bf2f(((const uint16_t*)RES)[idx]);
          const float sg = g / (1.0f + __expf(-g));
          ((uint16_t*)Cout)[idx] = f2bf(sg * v);
        }
      }
    }
  }
}

// ---------- flash attention with alibi + causal ----------
// qkv bf16 [2048][6144] (q|k thirds), vT bf16 [2048 c][2048 t],
// alibi f32 [16][2048][2048], Y bf16 [2048][2048].
// 2-deep pipeline: one barrier/iter; K/V double-buffered via global_load_lds
// (pre-swizzled source); alibi prefetched one tile ahead into registers.
__global__ __launch_bounds__(256, 2) void attn_kernel(const uint16_t* __restrict__ qkv,
                                                      const uint16_t* __restrict__ vT,
                                                      const float* __restrict__ alibi,
                                                      uint16_t* __restrict__ Y) {
  const int h = blockIdx.y;
  const int qt = 31 - blockIdx.x;  // heavy tiles dispatch first
  const int tid = threadIdx.x;
  const int lane = tid & 63;
  const int w = tid >> 6;
  const int l15 = lane & 15, l4 = lane >> 4;

  __shared__ uint16_t Ks[2][64 * 128];  // [kv][d], swizzled (swz)
  __shared__ uint16_t Vs[2][128 * 64];  // [d][kv] (V^T), swizzled (vswz)
  __shared__ uint16_t Ps[4][16 * 64];   // per-wave P tile [q][kv], swizzled

  const float scale = 0.08838834764831845f;  // 1/sqrt(128)

  auto stage = [&](int kv0, int b) {
    #pragma unroll
    for (int i = 0; i < 4; i++) {
      const int u = tid + i * 256;          // 16B unit 0..1023
      const int r = u >> 4;                 // K row
      const int c = (u & 15) ^ ((r & 7) ^ ((r >> 3) & 7));
      async_copy16(qkv + (size_t)(kv0 + r) * 6144 + 2048 + h * 128 + c * 8,
                   (char*)Ks[b] + u * 16);
    }
    #pragma unroll
    for (int i = 0; i < 4; i++) {
      const int u = tid + i * 256;
      const int r = u >> 3;                 // V^T row (d)
      const int c = (u & 7) ^ (r & 7);
      async_copy16(vT + (size_t)(h * 128 + r) * 2048 + kv0 + c * 8,
                   (char*)Vs[b] + u * 16);
    }
  };
  auto load_al = [&](int kv0, float (&al)[4][4]) {
    #pragma unroll
    for (int r = 0; r < 4; r++) {
      const size_t rowb = ((size_t)h * 2048 + (qt * 64 + w * 16 + l4 * 4 + r)) * 2048;
      #pragma unroll
      for (int nf = 0; nf < 4; nf++)
        al[nf][r] = alibi[rowb + kv0 + nf * 16 + l15];
    }
  };

  // Q fragments in registers: wave w owns q rows qt*64 + w*16 + [0,16)
  const int qrow = qt * 64 + w * 16 + l15;
  bf8_t qf[4];
  #pragma unroll
  for (int kc = 0; kc < 4; kc++)
    qf[kc] = *(const bf8_t*)(qkv + (size_t)qrow * 6144 + h * 128 + kc * 32 + l4 * 8);

  f32x4 accy[8];
  #pragma unroll
  for (int i = 0; i < 8; i++) accy[i] = 0.0f;
  float mrun[4], lrun[4];
  #pragma unroll
  for (int r = 0; r < 4; r++) { mrun[r] = -1e30f; lrun[r] = 0.0f; }

  stage(0, 0);
  float al[4][4];
  load_al(0, al);

  for (int kvt = 0; kvt <= qt; kvt++) {
    const int b = kvt & 1;
    const int kv0 = kvt * 64;
    __syncthreads();  // staging for tile kvt (and its alibi) drained here

    const int kvn = (kvt < qt) ? (kvt + 1) : qt;
    float aln[4][4];
    load_al(kvn * 64, aln);
    stage(kvn * 64, b ^ 1);

    // S = Q K^T * scale + alibi, causal mask
    float s[4][4];  // [nf][r]
    #pragma unroll
    for (int nf = 0; nf < 4; nf++) {
      f32x4 sa = 0.0f;
      const int krow = nf * 16 + l15;
      #pragma unroll
      for (int kc = 0; kc < 4; kc++) {
        bf8_t kb = *(const bf8_t*)((const char*)Ks[b] +
                                   ((krow * 256 + kc * 64 + l4 * 16) ^ swz(krow)));
        sa = __builtin_amdgcn_mfma_f32_16x16x32_bf16(qf[kc], kb, sa, 0, 0, 0);
      }
      const int kvcol = kv0 + nf * 16 + l15;
      #pragma unroll
      for (int r = 0; r < 4; r++) {
        const int q = qt * 64 + w * 16 + l4 * 4 + r;
        float sv = sa[r] * scale + al[nf][r];
        if (kvcol > q) sv = -1e30f;
        s[nf][r] = sv;
      }
    }

    // online softmax (wave-parallel row reduce over the 16 lanes of each row)
    #pragma unroll
    for (int r = 0; r < 4; r++) {
      float rm = fmaxf(fmaxf(s[0][r], s[1][r]), fmaxf(s[2][r], s[3][r]));
      rm = fmaxf(rm, __shfl_xor(rm, 1));
      rm = fmaxf(rm, __shfl_xor(rm, 2));
      rm = fmaxf(rm, __shfl_xor(rm, 4));
      rm = fmaxf(rm, __shfl_xor(rm, 8));
      const float mnew = fmaxf(mrun[r], rm);
      const float alpha = __expf(mrun[r] - mnew);
      mrun[r] = mnew;
      float rs = 0.0f;
      #pragma unroll
      for (int nf = 0; nf < 4; nf++) {
        const float p = __expf(s[nf][r] - mnew);
        s[nf][r] = p;
        rs += p;
      }
      rs += __shfl_xor(rs, 1);
      rs += __shfl_xor(rs, 2);
      rs += __shfl_xor(rs, 4);
      rs += __shfl_xor(rs, 8);
      lrun[r] = lrun[r] * alpha + rs;
      #pragma unroll
      for (int df = 0; df < 8; df++) accy[df][r] *= alpha;
    }

    // P -> LDS (bf16, swizzled), wave-private region
    #pragma unroll
    for (int nf = 0; nf < 4; nf++) {
      #pragma unroll
      for (int r = 0; r < 4; r++) {
        const int rq = l4 * 4 + r;
        const int bo = (rq * 128 + (nf * 16 + l15) * 2) ^ vswz(rq);
        *(uint16_t*)((char*)Ps[w] + bo) = f2bf(s[nf][r]);
      }
    }

    // PV: accy += P * V
    #pragma unroll
    for (int kk = 0; kk < 2; kk++) {
      bf8_t pa = *(const bf8_t*)((const char*)Ps[w] +
                                 ((l15 * 128 + kk * 64 + l4 * 16) ^ vswz(l15)));
      #pragma unroll
      for (int df = 0; df < 8; df++) {
        const int vr = df * 16 + l15;
        bf8_t vb = *(const bf8_t*)((const char*)Vs[b] +
                                   ((vr * 128 + kk * 64 + l4 * 16) ^ vswz(vr)));
        accy[df] = __builtin_amdgcn_mfma_f32_16x16x32_bf16(pa, vb, accy[df], 0, 0, 0);
      }
    }

    #pragma unroll
    for (int nf = 0; nf < 4; nf++)
      #pragma unroll
      for (int r = 0; r < 4; r++) al[nf][r] = aln[nf][r];
  }

  // epilogue: Y[q][h*128+d] = accy / lsum
  #pragma unroll
  for (int df = 0; df < 8; df++) {
    #pragma unroll
    for (int r = 0; r < 4; r++) {
      const int row = qt * 64 + w * 16 + l4 * 4 + r;
      const int col = h * 128 + df * 16 + l15;
      Y[(size_t)row * 2048 + col] = f2bf(accy[df][r] / lrun[r]);
    }
  }
}

// ---------- launch ----------
extern "C" void kernel_launch(void* const* d_in, const int* in_sizes, int n_in,
                              void* d_out, int out_size, void* d_ws, size_t ws_size,
                              hipStream_t stream) {
  const float* x      = (const float*)d_in[0];
  const float* alibi  = (const float*)d_in[1];
  const float* w_attn = (const float*)d_in[2];
  const float* w_proj = (const float*)d_in[3];
  const float* w_fc1  = (const float*)d_in[4];
  const float* w_fc2  = (const float*)d_in[5];
  const float* w_mp   = (const float*)d_in[6];
  const float* rms1   = (const float*)d_in[7];
  const float* rms2   = (const float*)d_in[8];
  float* out = (float*)d_out;

  char* ws = (char*)d_ws;
  uint16_t* xn      = (uint16_t*)(ws + 0);          //  8.39 MB [2048][2048]
  uint16_t* qkv     = (uint16_t*)(ws + 8388608);    // 25.17 MB [2048][6144]
  uint16_t* y       = (uint16_t*)(ws + 33554432);   //  8.39 MB [2048][2048]
  uint16_t* g1      = (uint16_t*)(ws + 41943040);   // 23.07 MB [2048][5632]
  uint16_t* hbuf    = (uint16_t*)(ws + 65011712);   // 23.07 MB [2048][5632]
  uint16_t* wt_attn = (uint16_t*)(ws + 88080384);   // 25.17 MB [6144][2048]
  uint16_t* wt_proj = (uint16_t*)(ws + 113246208);  //  8.39 MB [2048][2048]
  uint16_t* wt_fc1  = (uint16_t*)(ws + 121634816);  // 23.07 MB [5632][2048]
  uint16_t* wt_fc2  = (uint16_t*)(ws + 144703488);  // 23.07 MB [5632][2048]
  uint16_t* wt_mp   = (uint16_t*)(ws + 167772160);  // 23.07 MB [2048][5632]
  uint16_t* vT      = (uint16_t*)(ws + 190840832);  //  8.39 MB [2048 c][2048 t]

  transpose_conv<<<dim3(6144 / 64, 2048 / 64), 256, 0, stream>>>(w_attn, wt_attn, 2048, 6144);
  transpose_conv<<<dim3(2048 / 64, 2048 / 64), 256, 0, stream>>>(w_proj, wt_proj, 2048, 2048);
  transpose_conv<<<dim3(5632 / 64, 2048 / 64), 256, 0, stream>>>(w_fc1, wt_fc1, 2048, 5632);
  transpose_conv<<<dim3(5632 / 64, 2048 / 64), 256, 0, stream>>>(w_fc2, wt_fc2, 2048, 5632);
  transpose_conv<<<dim3(2048 / 64, 5632 / 64), 256, 0, stream>>>(w_mp, wt_mp, 5632, 2048);

  rmsnorm_kernel<<<2048, 256, 0, stream>>>(x, rms1, xn);

  gemm_bt<EPI_BF16><<<dim3(6144 / 128, 2048 / 128), 256, 0, stream>>>(
      xn, wt_attn, qkv, nullptr, 2048, 6144, 2048);

  transpose_v<<<dim3(32, 32), 256, 0, stream>>>(qkv, vT);

  attn_kernel<<<dim3(32, 16), 256, 0, stream>>>(qkv, vT, alibi, y);

  gemm_bt<EPI_ADDF32><<<dim3(2048 / 128, 2048 / 128), 256, 0, stream>>>(
      y, wt_proj, out, x, 2048, 2048, 2048);

  rmsnorm_kernel<<<2048, 256, 0, stream>>>(out, rms2, xn);

  gemm_bt<EPI_BF16><<<dim3(5632 / 128, 2048 / 128), 256, 0, stream>>>(
      xn, wt_fc1, g1, nullptr, 2048, 5632, 2048);

  gemm_bt<EPI_SILUMUL><<<dim3(5632 / 128, 2048 / 128), 256, 0, stream>>>(
      xn, wt_fc2, hbuf, g1, 2048, 5632, 2048);

  gemm_bt<EPI_ADDF32><<<dim3(2048 / 128, 2048 / 128), 256, 0, stream>>>(
      hbuf, wt_mp, out, out, 2048, 2048, 5632);
}